// Round 3
// baseline (22.573 us; speedup 1.0000x reference)
//
#include <hip/hip_runtime.h>

// 8-qubit effective circuit (reference qubits 8..10 stay |0>).
// Physical layout: 2 batch elements per wave; per element, physical index
// i in [0,256): i = lane*4 + j (lane = i[7:2], reg j = i[1:0]).
// CNOT ring layers tracked as GF(2) relabeling T_m = P^m (never executed).
// RY on logical bit b at layer m = XOR-butterfly with physical mask
// M = T_m^{-1} e_b, sign parity(row_b(T_m) & i). Per layer, a constexpr
// search chooses merged gate-pairs vs singles to minimize block-shuffles.

namespace {

struct M8 { unsigned r[8]; };

constexpr M8 kI{{0x01,0x02,0x04,0x08,0x10,0x20,0x40,0x80}};
constexpr M8 kP{{0xFF,0xFE,0xFC,0xF8,0xF0,0xE0,0xC0,0x7F}};
constexpr M8 kQ{{0x03,0x06,0x0C,0x18,0x30,0x60,0xC1,0x81}};

constexpr M8 mul(const M8& A, const M8& B) {
  M8 C{{0,0,0,0,0,0,0,0}};
  for (int j = 0; j < 8; ++j) {
    unsigned by = 0;
    for (int b = 0; b < 8; ++b) by |= ((B.r[b] >> j) & 1u) << b;
    for (int b = 0; b < 8; ++b) {
      unsigned v = A.r[b] & by;
      v ^= v >> 4; v ^= v >> 2; v ^= v >> 1;
      C.r[b] |= (v & 1u) << j;
    }
  }
  return C;
}

constexpr bool eqI(const M8& A) {
  bool e = true;
  for (int b = 0; b < 8; ++b) e = e && (A.r[b] == (1u << b));
  return e;
}

struct Tables { unsigned Mm[21][8]; unsigned Rr[21][8]; bool ok; };

constexpr Tables build() {
  Tables t{};
  M8 T = kI, Ti = kI;
  bool ok = eqI(mul(kP, kQ)) && eqI(mul(kQ, kP));
  for (int m = 0; m <= 20; ++m) {
    ok = ok && eqI(mul(T, Ti));
    for (int b = 0; b < 8; ++b) {
      unsigned mm = 0;
      for (int k = 0; k < 8; ++k) mm |= ((Ti.r[k] >> b) & 1u) << k;
      t.Mm[m][b] = mm;
      t.Rr[m][b] = T.r[b];
    }
    T = mul(kP, T);
    Ti = mul(Ti, kQ);
  }
  t.ok = ok;
  return t;
}

constexpr Tables kT = build();
static_assert(kT.ok, "GF(2) inverse tracking failed");

// ---- per-layer op scheduling (constexpr search over partial matchings) ----
// cost units: 8 per block-shuffle (4 swizzle instrs) + 1 per op (depth)
constexpr int single_cost(int m, int a) {
  return (((kT.Mm[m][a] >> 2) != 0) ? 8 : 0) + 1;
}
constexpr int pair_cost(int m, int a, int b) {
  const unsigned LA = kT.Mm[m][a] >> 2, LB = kT.Mm[m][b] >> 2, LC = LA ^ LB;
  int c = 0;
  if (LA) ++c;
  if (LB && LB != LA) ++c;
  if (LC && LC != LA && LC != LB) ++c;
  return 8 * c + 1;
}

struct PlanCost { int n; int pa[8]; int pb[8]; int cost; };

constexpr PlanCost search(int m, unsigned used) {
  if (used == 0xFFu) {
    PlanCost r{0, {0,0,0,0,0,0,0,0}, {0,0,0,0,0,0,0,0}, 0};
    return r;
  }
  int a = 0;
  while ((used >> a) & 1u) ++a;
  PlanCost best = search(m, used | (1u << a));
  best.pa[best.n] = a; best.pb[best.n] = -1;
  best.n += 1; best.cost += single_cost(m, a);
  for (int b = a + 1; b < 8; ++b) {
    if ((used >> b) & 1u) continue;
    PlanCost sub = search(m, used | (1u << a) | (1u << b));
    const int c = sub.cost + pair_cost(m, a, b);
    if (c < best.cost) {
      sub.pa[sub.n] = a; sub.pb[sub.n] = b;
      sub.n += 1; sub.cost = c;
      best = sub;
    }
  }
  return best;
}

struct AllPlans { int nops[21]; int pa[21][8]; int pb[21][8]; };

constexpr AllPlans build_plans() {
  AllPlans ap{};
  for (int m = 0; m < 21; ++m) {
    const PlanCost pc = search(m, 0u);
    ap.nops[m] = pc.n;
    for (int k = 0; k < 8; ++k) {
      ap.pa[m][k] = (k < pc.n) ? pc.pa[k] : 0;
      ap.pb[m][k] = (k < pc.n) ? pc.pb[k] : -1;
    }
  }
  return ap;
}

constexpr AllPlans kPlans = build_plans();

constexpr bool plans_ok() {
  for (int m = 0; m < 21; ++m) {
    unsigned mask = 0; int cnt = 0;
    for (int k = 0; k < kPlans.nops[m]; ++k) {
      mask |= 1u << kPlans.pa[m][k]; ++cnt;
      if (kPlans.pb[m][k] >= 0) { mask |= 1u << kPlans.pb[m][k]; ++cnt; }
    }
    if (mask != 0xFFu || cnt != 8) return false;
  }
  return true;
}
static_assert(plans_ok(), "bad gate schedule");

__constant__ AllPlans dPlans = build_plans();  // runtime copy for table setup

struct LaneSet { unsigned L[3]; };
constexpr LaneSet lane_set(unsigned a, unsigned b, unsigned c) {
  LaneSet r{{0,0,0}}; int n = 0;
  const unsigned v[3] = {a, b, c};
  for (int i = 0; i < 3; ++i) {
    if (!v[i]) continue;
    bool dup = false;
    for (int j = 0; j < n; ++j) if (r.L[j] == v[i]) dup = true;
    if (!dup) r.L[n++] = v[i];
  }
  return r;
}

template<unsigned RX, int IDX>
__device__ __forceinline__ float pick(const float (&s)[4], const float (&t0)[4],
                                      const float (&t1)[4], const float (&t2)[4], int j) {
  if constexpr (IDX == 0) return t0[j ^ (int)RX];
  else if constexpr (IDX == 1) return t1[j ^ (int)RX];
  else if constexpr (IDX == 2) return t2[j ^ (int)RX];
  else return s[j ^ (int)RX];
}

template<int m, int op>
__device__ __forceinline__ void do_op(int lane, const float4* __restrict__ ct4,
                                      float (&s)[4], float (&u)[4]) {
  constexpr int ga = kPlans.pa[m][op];
  constexpr int gb = kPlans.pb[m][op];
  constexpr unsigned MA = kT.Mm[m][ga];
  constexpr unsigned RA = kT.Rr[m][ga];
  constexpr unsigned LA = MA >> 2;
  const float4 k = ct4[m * 8 + op];

  if constexpr (gb < 0) {
    // single RY gate: out = c*in + (+-s)*partner
    float tAs[4], tAu[4];
    #pragma unroll
    for (int j = 0; j < 4; ++j) {
      float ps = s[j ^ (int)(MA & 3u)];
      float pu = u[j ^ (int)(MA & 3u)];
      if constexpr (LA != 0) { ps = __shfl_xor(ps, (int)LA); pu = __shfl_xor(pu, (int)LA); }
      tAs[j] = ps; tAu[j] = pu;
    }
    const int sa = __popc((int)(RA >> 2) & lane) & 1;
    const float wa = sa ? -k.y : k.y;
    float ns[4], nu[4];
    #pragma unroll
    for (int j = 0; j < 4; ++j) {
      const int pj = __popc((int)(RA & 3u) & j) & 1;
      const float va = pj ? -wa : wa;
      ns[j] = fmaf(va, tAs[j], k.x * s[j]);
      nu[j] = fmaf(va, tAu[j], k.x * u[j]);
    }
    #pragma unroll
    for (int j = 0; j < 4; ++j) { s[j] = ns[j]; u[j] = nu[j]; }
  } else {
    // merged pair of commuting RY gates: 4-point butterfly
    constexpr unsigned MB = kT.Mm[m][gb], MC = MA ^ MB;
    constexpr unsigned RB = kT.Rr[m][gb];
    constexpr unsigned LB = MB >> 2, LC = MC >> 2;
    constexpr LaneSet LS = lane_set(LA, LB, LC);
    constexpr unsigned L1 = LS.L[0], L2 = LS.L[1], L3 = LS.L[2];
    constexpr int iA = (LA == 0) ? -1 : (LA == L1 ? 0 : (LA == L2 ? 1 : 2));
    constexpr int iB = (LB == 0) ? -1 : (LB == L1 ? 0 : (LB == L2 ? 1 : 2));
    constexpr int iC = (LC == 0) ? -1 : (LC == L1 ? 0 : (LC == L2 ? 1 : 2));

    float b1s[4], b1u[4], b2s[4], b2u[4], b3s[4], b3u[4];
    if constexpr (L1 != 0) {
      #pragma unroll
      for (int j = 0; j < 4; ++j) { b1s[j] = __shfl_xor(s[j], (int)L1); b1u[j] = __shfl_xor(u[j], (int)L1); }
    }
    if constexpr (L2 != 0) {
      #pragma unroll
      for (int j = 0; j < 4; ++j) { b2s[j] = __shfl_xor(s[j], (int)L2); b2u[j] = __shfl_xor(u[j], (int)L2); }
    }
    if constexpr (L3 != 0) {
      #pragma unroll
      for (int j = 0; j < 4; ++j) { b3s[j] = __shfl_xor(s[j], (int)L3); b3u[j] = __shfl_xor(u[j], (int)L3); }
    }

    const int sa = __popc((int)(RA >> 2) & lane) & 1;
    const int sb = __popc((int)(RB >> 2) & lane) & 1;
    const float wa = sa ? -k.y : k.y;
    const float wb = sb ? -k.z : k.z;
    const float wc = (sa ^ sb) ? -k.w : k.w;

    float ns[4], nu[4];
    #pragma unroll
    for (int j = 0; j < 4; ++j) {
      const int pa_ = __popc((int)(RA & 3u) & j) & 1;
      const int pb_ = __popc((int)(RB & 3u) & j) & 1;
      const float vA = pa_ ? -wa : wa;
      const float vB = pb_ ? -wb : wb;
      const float vC = (pa_ ^ pb_) ? -wc : wc;
      ns[j] = fmaf(vC, pick<MC & 3u, iC>(s, b1s, b2s, b3s, j),
              fmaf(vB, pick<MB & 3u, iB>(s, b1s, b2s, b3s, j),
              fmaf(vA, pick<MA & 3u, iA>(s, b1s, b2s, b3s, j), k.x * s[j])));
      nu[j] = fmaf(vC, pick<MC & 3u, iC>(u, b1u, b2u, b3u, j),
              fmaf(vB, pick<MB & 3u, iB>(u, b1u, b2u, b3u, j),
              fmaf(vA, pick<MA & 3u, iA>(u, b1u, b2u, b3u, j), k.x * u[j])));
    }
    #pragma unroll
    for (int j = 0; j < 4; ++j) { s[j] = ns[j]; u[j] = nu[j]; }
  }
}

template<int m, int op>
__device__ __forceinline__ void run_ops(int lane, const float4* __restrict__ ct4,
                                        float (&s)[4], float (&u)[4]) {
  if constexpr (op < kPlans.nops[m]) {
    do_op<m, op>(lane, ct4, s, u);
    run_ops<m, op + 1>(lane, ct4, s, u);
  }
}

template<int m>
__device__ __forceinline__ void run_all(int lane, const float4* __restrict__ ct4,
                                        float (&s)[4], float (&u)[4]) {
  if constexpr (m <= 20) {
    run_ops<m, 0>(lane, ct4, s, u);
    run_all<m + 1>(lane, ct4, s, u);
  }
}

}  // namespace

__global__ __launch_bounds__(128) void qae_kernel(const float* __restrict__ x,
                                                  const float* __restrict__ theta,
                                                  float* __restrict__ out) {
  __shared__ float4 ct4[168];  // [21 layers][8 op slots]
  const int t = threadIdx.x;
  for (int tt = t; tt < 168; tt += 128) {
    const int m = tt >> 3, op = tt & 7;
    if (op < dPlans.nops[m]) {
      const int ga = dPlans.pa[m][op], gb = dPlans.pb[m][op];
      float sA, cA;
      sincosf(theta[m * 8 + (7 - ga)] * 0.5f, &sA, &cA);
      if (gb >= 0) {
        float sB, cB;
        sincosf(theta[m * 8 + (7 - gb)] * 0.5f, &sB, &cB);
        ct4[tt] = make_float4(cA * cB, sA * cB, cA * sB, sA * sB);
      } else {
        ct4[tt] = make_float4(cA, sA, 0.f, 0.f);
      }
    }
  }
  __syncthreads();

  const int lane = t & 63;
  const int wave = t >> 6;
  const int b0 = blockIdx.x * 4 + wave * 2;

  const float4 xv0 = *reinterpret_cast<const float4*>(x + (size_t)b0 * 256 + lane * 4);
  const float4 xv1 = *reinterpret_cast<const float4*>(x + (size_t)(b0 + 1) * 256 + lane * 4);
  float s[4] = {xv0.x, xv0.y, xv0.z, xv0.w};
  float u[4] = {xv1.x, xv1.y, xv1.z, xv1.w};

  run_all<0>(lane, ct4, s, u);

  // output bucket B = logical bits 0..2 (parities of rows of T_20)
  constexpr unsigned R0 = kT.Rr[20][0], R1 = kT.Rr[20][1], R2 = kT.Rr[20][2];
  const int q0 = __popc((int)(R0 >> 2) & lane) & 1;
  const int q1 = __popc((int)(R1 >> 2) & lane) & 1;
  const int q2 = __popc((int)(R2 >> 2) & lane) & 1;

  float accS[8], accU[8];
  #pragma unroll
  for (int B = 0; B < 8; ++B) { accS[B] = 0.f; accU[B] = 0.f; }
  #pragma unroll
  for (int j = 0; j < 4; ++j) {
    const int bj = (q0 ^ (__popc((int)(R0 & 3u) & j) & 1))
                 | ((q1 ^ (__popc((int)(R1 & 3u) & j) & 1)) << 1)
                 | ((q2 ^ (__popc((int)(R2 & 3u) & j) & 1)) << 2);
    const float ps = s[j] * s[j];
    const float pu = u[j] * u[j];
    #pragma unroll
    for (int B = 0; B < 8; ++B) {
      accS[B] += (bj == B) ? ps : 0.f;
      accU[B] += (bj == B) ? pu : 0.f;
    }
  }
  #pragma unroll
  for (int mm = 1; mm < 64; mm <<= 1) {
    #pragma unroll
    for (int B = 0; B < 8; ++B) {
      accS[B] += __shfl_xor(accS[B], mm);
      accU[B] += __shfl_xor(accU[B], mm);
    }
  }
  if (lane == 0) {
    float4* o = reinterpret_cast<float4*>(out + (size_t)b0 * 8);
    o[0] = make_float4(accS[0], accS[1], accS[2], accS[3]);
    o[1] = make_float4(accS[4], accS[5], accS[6], accS[7]);
  } else if (lane == 1) {
    float4* o = reinterpret_cast<float4*>(out + (size_t)(b0 + 1) * 8);
    o[0] = make_float4(accU[0], accU[1], accU[2], accU[3]);
    o[1] = make_float4(accU[4], accU[5], accU[6], accU[7]);
  }
}

extern "C" void kernel_launch(void* const* d_in, const int* in_sizes, int n_in,
                              void* d_out, int out_size, void* d_ws, size_t ws_size,
                              hipStream_t stream) {
  const float* x = (const float*)d_in[0];      // [1024, 256]
  const float* theta = (const float*)d_in[1];  // [168]
  float* out = (float*)d_out;                  // [1024, 8]
  qae_kernel<<<256, 128, 0, stream>>>(x, theta, out);
}